// Round 7
// baseline (201.138 us; speedup 1.0000x reference)
//
#include <hip/hip_runtime.h>

#define NPTS 2048
#define TPB  512   // 4 elems/thread; 8 waves/block = 2 waves/SIMD

typedef float v4f __attribute__((ext_vector_type(4)));

// Barrier WITHOUT the vmcnt(0) drain __syncthreads() would emit:
// LDS writes must be visible (lgkmcnt), global stores may stay in flight.
#define EDGE_BARRIER() do {                                   \
    asm volatile("s_waitcnt lgkmcnt(0)" ::: "memory");        \
    __builtin_amdgcn_s_barrier();                             \
    asm volatile("" ::: "memory");                            \
} while (0)

// g = 0.5*f(u) = u*(0.75 + u*(9.375 + u*(-25.25 + u*(18.75 - 3.125 u^2))))
// p = f'(u)    = 1.5 + u*(37.5 + u*(-151.5 + u*(150 - 37.5 u^2)))
__device__ __forceinline__ void eval_gp(float u, float& g, float& p) {
    const float uu = u * u;
    float gg = fmaf(uu, -3.125f, 18.75f);
    gg = fmaf(u, gg, -25.25f);
    gg = fmaf(u, gg, 9.375f);
    gg = fmaf(u, gg, 0.75f);
    g = u * gg;
    float pp = fmaf(uu, -37.5f, 150.0f);
    pp = fmaf(u, pp, -151.5f);
    pp = fmaf(u, pp, 37.5f);
    p = fmaf(u, pp, 1.5f);
}

__global__ __launch_bounds__(TPB) void lxf_persist(
    const float* __restrict__ init, float* __restrict__ out,
    int nbatch, int nsteps)
{
    // Full 4-elem state published per thread; halo width 2 consumed each side.
    __shared__ v4f e[2][TPB];

    const int b   = blockIdx.x;
    const int tid = threadIdx.x;
    const size_t rowoff = (size_t)b * NPTS;
    const float lam = 0.1024f;                 // DT/DX (exact in f32)

    // ---- load init chunk, write t=0, seed edge buffer ----
    const v4f* src = reinterpret_cast<const v4f*>(init + rowoff);
    v4f a0 = src[tid];
    float s0 = a0.x, s1 = a0.y, s2 = a0.z, s3 = a0.w;

    {
        v4f* dst0 = reinterpret_cast<v4f*>(out + rowoff);
        dst0[tid] = a0;
        e[0][tid] = a0;
    }
    EDGE_BARRIER();

    const size_t stride_t4 = ((size_t)nbatch * NPTS) / 4;  // v4fs per step
    const int tl = (tid == 0)       ? 0       : tid - 1;
    const int tr = (tid == TPB - 1) ? TPB - 1 : tid + 1;
    const bool left  = (tid == 0);
    const bool right = (tid == TPB - 1);

    v4f* dstw = reinterpret_cast<v4f*>(out + rowoff);
    int cur = 0;

    const int S = nsteps - 1;       // advance steps (499)
    const int P = S >> 1;           // double-steps (249)

    for (int i = 0; i < P; ++i) {
        const int nxt = cur ^ 1;

        // ---- window y[0..7] = u[4*tid - 2 .. 4*tid + 5] ----
        const v4f eL = e[cur][tl];
        const v4f eR = e[cur][tr];
        float y[8];
        y[0] = eL.z; y[1] = eL.w;
        y[2] = s0;   y[3] = s1;   y[4] = s2;   y[5] = s3;
        y[6] = eR.x; y[7] = eR.y;
        if (left)  { y[0] = s0; y[1] = s0; }   // values never reach own elems
        if (right) { y[6] = s3; y[7] = s3; }

        // ---- sub-step 1: y[0..7] -> z[0..5] = u'[4t-1 .. 4t+4] ----
        float g[8], p[8];
        #pragma unroll
        for (int k = 0; k < 8; ++k) eval_gp(y[k], g[k], p[k]);
        float fh[7];
        #pragma unroll
        for (int j = 0; j < 7; ++j) {
            const float alpha = fmaxf(fabsf(p[j]), fabsf(p[j + 1]));
            fh[j] = fmaf(-0.5f * alpha, y[j + 1] - y[j], g[j] + g[j + 1]);
        }
        float z[6];
        #pragma unroll
        for (int m = 0; m < 6; ++m)
            z[m] = fmaf(-lam, fh[m + 1] - fh[m], y[m + 1]);
        // BC after sub-step 1 (z[1] is u'[0] for tid0; z[4] is u'[N-1] for last)
        if (left)  { z[1] = z[2]; z[0] = z[2]; }
        if (right) { z[4] = z[3]; z[5] = z[3]; }

        // store u' (own elems = z[1..4])
        dstw += stride_t4;
        v4f w1v; w1v.x = z[1]; w1v.y = z[2]; w1v.z = z[3]; w1v.w = z[4];
        dstw[tid] = w1v;

        // ---- sub-step 2: z[0..5] -> w[0..3] = u''[4t .. 4t+3] ----
        float g2[6], p2[6];
        #pragma unroll
        for (int k = 0; k < 6; ++k) eval_gp(z[k], g2[k], p2[k]);
        float f2[5];
        #pragma unroll
        for (int j = 0; j < 5; ++j) {
            const float alpha = fmaxf(fabsf(p2[j]), fabsf(p2[j + 1]));
            f2[j] = fmaf(-0.5f * alpha, z[j + 1] - z[j], g2[j] + g2[j + 1]);
        }
        float w[4];
        #pragma unroll
        for (int m = 0; m < 4; ++m)
            w[m] = fmaf(-lam, f2[m + 1] - f2[m], z[m + 1]);
        if (left)  w[0] = w[1];
        if (right) w[3] = w[2];

        // publish halos for the next pair FIRST, then store u''
        v4f wv; wv.x = w[0]; wv.y = w[1]; wv.z = w[2]; wv.w = w[3];
        e[nxt][tid] = wv;
        dstw += stride_t4;
        dstw[tid] = wv;

        s0 = w[0]; s1 = w[1]; s2 = w[2]; s3 = w[3];
        cur = nxt;
        EDGE_BARRIER();
    }

    // ---- odd tail: one single step ----
    if (S & 1) {
        const v4f eL = e[cur][tl];
        const v4f eR = e[cur][tr];
        float y[6];
        y[1] = s0; y[2] = s1; y[3] = s2; y[4] = s3;
        y[0] = left  ? s0 : eL.w;
        y[5] = right ? s3 : eR.x;

        float g[6], p[6];
        #pragma unroll
        for (int k = 0; k < 6; ++k) eval_gp(y[k], g[k], p[k]);
        float fh[5];
        #pragma unroll
        for (int j = 0; j < 5; ++j) {
            const float alpha = fmaxf(fabsf(p[j]), fabsf(p[j + 1]));
            fh[j] = fmaf(-0.5f * alpha, y[j + 1] - y[j], g[j] + g[j + 1]);
        }
        float u0 = fmaf(-lam, fh[1] - fh[0], y[1]);
        float u1 = fmaf(-lam, fh[2] - fh[1], y[2]);
        float u2 = fmaf(-lam, fh[3] - fh[2], y[3]);
        float u3 = fmaf(-lam, fh[4] - fh[3], y[4]);
        if (left)  u0 = u1;
        if (right) u3 = u2;

        dstw += stride_t4;
        v4f wv; wv.x = u0; wv.y = u1; wv.z = u2; wv.w = u3;
        dstw[tid] = wv;
    }
}

extern "C" void kernel_launch(void* const* d_in, const int* in_sizes, int n_in,
                              void* d_out, int out_size, void* d_ws, size_t ws_size,
                              hipStream_t stream) {
    const float* init = (const float*)d_in[0];
    float* out = (float*)d_out;

    const int nbatch = in_sizes[0] / NPTS;       // 128
    const int nsteps = out_size / in_sizes[0];   // 500

    hipLaunchKernelGGL(lxf_persist, dim3(nbatch), dim3(TPB), 0, stream,
                       init, out, nbatch, nsteps);
}

// Round 8
// 165.083 us; speedup vs baseline: 1.2184x; 1.2184x over previous
//
#include <hip/hip_runtime.h>

#define NPTS 2048
#define TPB  768    // 12 waves/block; 2 cells/thread; capacity 1536
#define CAP  1536   // own 1024 + 512 ghost wedge (>= 499 steps of cone)
#define OWN  1024

typedef float v2f __attribute__((ext_vector_type(2)));

// Barrier WITHOUT the vmcnt(0) drain __syncthreads() would emit:
// LDS writes must be visible (lgkmcnt), global stores may stay in flight.
#define EDGE_BARRIER() do {                                   \
    asm volatile("s_waitcnt lgkmcnt(0)" ::: "memory");        \
    __builtin_amdgcn_s_barrier();                             \
    asm volatile("" ::: "memory");                            \
} while (0)

// g = 0.5*f(u) = u*(0.75 + u*(9.375 + u*(-25.25 + u*(18.75 - 3.125 u^2))))
// p = f'(u)    = 1.5 + u*(37.5 + u*(-151.5 + u*(150 - 37.5 u^2)))
__device__ __forceinline__ void eval_gp(float u, float& g, float& p) {
    const float uu = u * u;
    float gg = fmaf(uu, -3.125f, 18.75f);
    gg = fmaf(u, gg, -25.25f);
    gg = fmaf(u, gg, 9.375f);
    gg = fmaf(u, gg, 0.75f);
    g = u * gg;
    float pp = fmaf(uu, -37.5f, 150.0f);
    pp = fmaf(u, pp, -151.5f);
    pp = fmaf(u, pp, 37.5f);
    p = fmaf(u, pp, 1.5f);
}

// Grid = 2 blocks per row (256 blocks -> all 256 CUs). Block (r,h) evolves
// 1536 cells autonomously: own 1024 + 512-wide ghost wedge toward the
// partner. Clamp-induced junk at the far edge advances 1 cell/step and
// reaches own cells only at t=512 > 499 -> own region is bit-exact.
__global__ __launch_bounds__(TPB) void lxf_split(
    const float* __restrict__ init, float* __restrict__ out,
    int nbatch, int nsteps)
{
    __shared__ float Ub[2][CAP];   // u
    __shared__ float Gb[2][CAP];   // g = 0.5*f(u)
    __shared__ float Pb[2][CAP];   // p = f'(u)

    const int blk = blockIdx.x;
    const int r   = blk >> 1;            // row
    const int h   = blk & 1;             // half: 0 -> global [0,1536), 1 -> [512,2048)
    const int tid = threadIdx.x;
    const int c0  = 2 * tid;             // local first cell
    const int gb  = h ? 512 : 0;         // local -> global offset
    const size_t rowoff = (size_t)r * NPTS;
    const float lam = 0.1024f;           // DT/DX (exact in f32)

    // own-cell mask (wave-uniform: boundary at thread 512 / 256)
    const bool st  = h ? (c0 >= 512) : (c0 < OWN);
    const bool bcL = (h == 0) && (tid == 0);        // global cell 0
    const bool bcR = (h == 1) && (tid == TPB - 1);  // global cell 2047
    const int  hl  = (tid == 0)       ? 0       : c0 - 1;   // clamped halo idx
    const int  hr  = (tid == TPB - 1) ? CAP - 1 : c0 + 2;

    // ---- load init cells, eval g/p, write t=0, publish buf 0 ----
    v2f uv = *reinterpret_cast<const v2f*>(init + rowoff + gb + c0);
    float u0 = uv.x, u1 = uv.y;
    float g0, p0, g1, p1;
    eval_gp(u0, g0, p0);
    eval_gp(u1, g1, p1);

    if (st) *reinterpret_cast<v2f*>(out + rowoff + gb + c0) = uv;

    {
        *reinterpret_cast<v2f*>(&Ub[0][c0]) = uv;
        v2f gv; gv.x = g0; gv.y = g1;
        *reinterpret_cast<v2f*>(&Gb[0][c0]) = gv;
        v2f pv; pv.x = p0; pv.y = p1;
        *reinterpret_cast<v2f*>(&Pb[0][c0]) = pv;
    }
    EDGE_BARRIER();

    const size_t stride = (size_t)nbatch * NPTS;    // floats per step
    float* dstw = out + rowoff + gb + c0;

#define STEP(CUR, NXT) do {                                            \
    dstw += stride;                                                    \
    const float uL = Ub[CUR][hl], gL = Gb[CUR][hl], pL = Pb[CUR][hl];  \
    const float uR = Ub[CUR][hr], gR = Gb[CUR][hr], pR = Pb[CUR][hr];  \
    /* fluxes at interfaces (L,0), (0,1), (1,R) */                     \
    const float aL = fmaxf(fabsf(pL), fabsf(p0));                      \
    const float aM = fmaxf(fabsf(p0), fabsf(p1));                      \
    const float aR = fmaxf(fabsf(p1), fabsf(pR));                      \
    const float fhL = fmaf(-0.5f * aL, u0 - uL, gL + g0);              \
    const float fhM = fmaf(-0.5f * aM, u1 - u0, g0 + g1);              \
    const float fhR = fmaf(-0.5f * aR, uR - u1, g1 + gR);              \
    float n0 = fmaf(-lam, fhM - fhL, u0);                              \
    float n1 = fmaf(-lam, fhR - fhM, u1);                              \
    if (bcL) n0 = n1;   /* u[0]    = u[1]    */                        \
    if (bcR) n1 = n0;   /* u[N-1]  = u[N-2]  */                        \
    eval_gp(n0, g0, p0);                                               \
    eval_gp(n1, g1, p1);                                               \
    v2f nv; nv.x = n0; nv.y = n1;                                      \
    *reinterpret_cast<v2f*>(&Ub[NXT][c0]) = nv;                        \
    v2f ngv; ngv.x = g0; ngv.y = g1;                                   \
    *reinterpret_cast<v2f*>(&Gb[NXT][c0]) = ngv;                       \
    v2f npv; npv.x = p0; npv.y = p1;                                   \
    *reinterpret_cast<v2f*>(&Pb[NXT][c0]) = npv;                       \
    if (st) *reinterpret_cast<v2f*>(dstw) = nv;                        \
    u0 = n0; u1 = n1;                                                  \
    EDGE_BARRIER();                                                    \
} while (0)

    const int S  = nsteps - 1;   // 499
    const int P2 = S >> 1;       // 249
    for (int i = 0; i < P2; ++i) {
        STEP(0, 1);
        STEP(1, 0);
    }
    if (S & 1) STEP(0, 1);
#undef STEP
}

extern "C" void kernel_launch(void* const* d_in, const int* in_sizes, int n_in,
                              void* d_out, int out_size, void* d_ws, size_t ws_size,
                              hipStream_t stream) {
    const float* init = (const float*)d_in[0];
    float* out = (float*)d_out;

    const int nbatch = in_sizes[0] / NPTS;       // 128
    const int nsteps = out_size / in_sizes[0];   // 500

    hipLaunchKernelGGL(lxf_split, dim3(2 * nbatch), dim3(TPB), 0, stream,
                       init, out, nbatch, nsteps);
}

// Round 9
// 157.575 us; speedup vs baseline: 1.2765x; 1.0476x over previous
//
#include <hip/hip_runtime.h>

#define NPTS 2048
#define TPB  768    // 12 waves/block; 2 cells/thread; capacity 1536
#define CAP  1536   // own 1024 + 512 ghost wedge (>= 499 steps of cone)

typedef float v2f __attribute__((ext_vector_type(2)));

// Barrier WITHOUT the vmcnt(0) drain __syncthreads() would emit:
// LDS writes must be visible (lgkmcnt), global stores may stay in flight.
#define EDGE_BARRIER() do {                                   \
    asm volatile("s_waitcnt lgkmcnt(0)" ::: "memory");        \
    __builtin_amdgcn_s_barrier();                             \
    asm volatile("" ::: "memory");                            \
} while (0)

__device__ __forceinline__ v2f s2(float x) { v2f v; v.x = x; v.y = x; return v; }

// packed fma: lowers to v_pk_fma_f32 on gfx90a+ (2 f32 FMA / lane / instr)
__device__ __forceinline__ v2f fma2(v2f a, v2f b, v2f c) {
#if __has_builtin(__builtin_elementwise_fma)
    return __builtin_elementwise_fma(a, b, c);
#else
    v2f r; r.x = fmaf(a.x, b.x, c.x); r.y = fmaf(a.y, b.y, c.y); return r;
#endif
}

// g = 0.5*f(u) = u*(0.75 + u*(9.375 + u*(-25.25 + u*(18.75 - 3.125 u^2))))
// p = f'(u)    = 1.5 + u*(37.5 + u*(-151.5 + u*(150 - 37.5 u^2)))
// Packed over the thread's two cells: 10 pk ops vs 19 scalar ops.
__device__ __forceinline__ void eval_gp2(v2f u, v2f& g, v2f& p) {
    const v2f uu = u * u;
    v2f gg = fma2(uu, s2(-3.125f), s2(18.75f));
    gg = fma2(u, gg, s2(-25.25f));
    gg = fma2(u, gg, s2(9.375f));
    gg = fma2(u, gg, s2(0.75f));
    g = u * gg;
    v2f pp = fma2(uu, s2(-37.5f), s2(150.0f));
    pp = fma2(u, pp, s2(-151.5f));
    pp = fma2(u, pp, s2(37.5f));
    p = fma2(u, pp, s2(1.5f));
}

// Grid = 2 blocks per row (256 blocks -> all 256 CUs). Block (r,h) evolves
// 1536 cells autonomously: own 1024 + 512-wide ghost wedge toward the
// partner. Clamp junk advances 1 cell/step: own region is bit-exact through
// t=499. Frontier: a wedge thread at cone-distance d is only needed while
// remaining steps >= d, then its wave retires (saves ~13% issue).
__global__ __launch_bounds__(TPB) void lxf_split(
    const float* __restrict__ init, float* __restrict__ out,
    int nbatch, int nsteps)
{
    __shared__ float Ub[2][CAP];   // u
    __shared__ float Gb[2][CAP];   // g = 0.5*f(u)
    __shared__ float Pb[2][CAP];   // p = f'(u)

    const int blk = blockIdx.x;
    const int r   = blk >> 1;            // row
    const int h   = blk & 1;             // 0 -> global [0,1536), 1 -> [512,2048)
    const int tid = threadIdx.x;
    const int c0  = 2 * tid;             // local first cell
    const int gb  = h ? 512 : 0;         // local -> global offset
    const size_t rowoff = (size_t)r * NPTS;
    const float lam = 0.1024f;           // DT/DX (exact in f32)

    const bool st  = h ? (c0 >= 512) : (c0 < 1024);      // own-cell store mask
    const bool bcL = (h == 0) && (tid == 0);             // global cell 0
    const bool bcR = (h == 1) && (tid == TPB - 1);       // global cell 2047
    const int  hl  = (tid == 0)       ? 0       : c0 - 1;
    const int  hr  = (tid == TPB - 1) ? CAP - 1 : c0 + 2;
    // cone distance into the wedge (margin 2); active while dist <= rem
    const int dist = h ? (509 - c0) : (c0 - 1025);

    // ---- load init cells, eval g/p, write t=0, publish buf 0 ----
    v2f uv = *reinterpret_cast<const v2f*>(init + rowoff + gb + c0);
    v2f gv, pv;
    eval_gp2(uv, gv, pv);

    if (st) *reinterpret_cast<v2f*>(out + rowoff + gb + c0) = uv;

    *reinterpret_cast<v2f*>(&Ub[0][c0]) = uv;
    *reinterpret_cast<v2f*>(&Gb[0][c0]) = gv;
    *reinterpret_cast<v2f*>(&Pb[0][c0]) = pv;
    EDGE_BARRIER();

    const size_t stride = (size_t)nbatch * NPTS;    // floats per step
    float* dstw = out + rowoff + gb + c0;

#define STEP(CUR, NXT) do {                                              \
    dstw += stride;                                                      \
    if (dist <= rem) {                                                   \
        const float uL = Ub[CUR][hl], gL = Gb[CUR][hl], pL = Pb[CUR][hl];\
        const float uR = Ub[CUR][hr], gR = Gb[CUR][hr], pR = Pb[CUR][hr];\
        const float aL = fmaxf(fabsf(pL), fabsf(pv.x));                  \
        const float aM = fmaxf(fabsf(pv.x), fabsf(pv.y));                \
        const float aR = fmaxf(fabsf(pv.y), fabsf(pR));                  \
        const float fhL = fmaf(-0.5f * aL, uv.x - uL, gL + gv.x);        \
        const float fhM = fmaf(-0.5f * aM, uv.y - uv.x, gv.x + gv.y);    \
        const float fhR = fmaf(-0.5f * aR, uR - uv.y, gv.y + gR);        \
        float n0 = fmaf(-lam, fhM - fhL, uv.x);                          \
        float n1 = fmaf(-lam, fhR - fhM, uv.y);                          \
        if (bcL) n0 = n1;   /* u[0]   = u[1]   */                        \
        if (bcR) n1 = n0;   /* u[N-1] = u[N-2] */                        \
        uv.x = n0; uv.y = n1;                                            \
        eval_gp2(uv, gv, pv);                                            \
        *reinterpret_cast<v2f*>(&Ub[NXT][c0]) = uv;                      \
        *reinterpret_cast<v2f*>(&Gb[NXT][c0]) = gv;                      \
        *reinterpret_cast<v2f*>(&Pb[NXT][c0]) = pv;                      \
        if (st) *reinterpret_cast<v2f*>(dstw) = uv;                      \
    }                                                                    \
    --rem;                                                               \
    EDGE_BARRIER();                                                      \
} while (0)

    const int S  = nsteps - 1;   // 499
    int rem = S - 1;             // remaining steps AFTER the current one
    const int P2 = S >> 1;       // 249
    for (int i = 0; i < P2; ++i) {
        STEP(0, 1);
        STEP(1, 0);
    }
    if (S & 1) STEP(0, 1);
#undef STEP
}

extern "C" void kernel_launch(void* const* d_in, const int* in_sizes, int n_in,
                              void* d_out, int out_size, void* d_ws, size_t ws_size,
                              hipStream_t stream) {
    const float* init = (const float*)d_in[0];
    float* out = (float*)d_out;

    const int nbatch = in_sizes[0] / NPTS;       // 128
    const int nsteps = out_size / in_sizes[0];   // 500

    hipLaunchKernelGGL(lxf_split, dim3(2 * nbatch), dim3(TPB), 0, stream,
                       init, out, nbatch, nsteps);
}